// Round 1
// baseline (89.537 us; speedup 1.0000x reference)
//
#include <hip/hip_runtime.h>

// DKNN via NeuralSort relaxation.
// Shapes: query [32,128] f32, neighbors [1024,128] f32, gumbel [2,32,1024] f32.
// Output: [2,32,1024] f32 = sum of first K=16 rows of relaxed permutation matrix.
//
// Numerics: c_r*s ~ -2.6e5 and B ~ 5e4; f32 ulp there (~0.03) would inject ~3%
// error into exp() after max-subtraction, vs a 2% absmax threshold. So s, B and
// t = c_r*s - B are computed/stored in f64; only exp runs in f32.

constexpr int NQ = 32;     // queries
constexpr int NN = 1024;   // neighbors
constexpr int ND = 128;    // dims
constexpr int NS = 2;      // PL samples
constexpr int NP = NS * NQ;  // 64 (sample,query) pairs
constexpr int KTOP = 16;

// ---------------------------------------------------------------- kernel 1
// s[p][j] = gumbel[p][j] - ||q_m - n_j||^2   (f64 accumulate)
__global__ __launch_bounds__(256) void k_scores(const float* __restrict__ q,
                                                const float* __restrict__ nb,
                                                const float* __restrict__ gum,
                                                double* __restrict__ s_out) {
  int p = blockIdx.x;          // p = sample*32 + m
  int m = p & 31;
  __shared__ float qs[ND];
  int tid = threadIdx.x;
  if (tid < ND) qs[tid] = q[m * ND + tid];
  __syncthreads();
  const float4* qs4 = (const float4*)qs;
#pragma unroll
  for (int jj = 0; jj < 4; ++jj) {
    int j = tid + jj * 256;
    const float4* nrow = (const float4*)(nb + (size_t)j * ND);
    double acc = 0.0;
#pragma unroll
    for (int d4 = 0; d4 < ND / 4; ++d4) {
      float4 n4 = nrow[d4];
      float4 q4 = qs4[d4];
      float dx = q4.x - n4.x, dy = q4.y - n4.y;
      float dz = q4.z - n4.z, dw = q4.w - n4.w;
      acc += (double)dx * dx + (double)dy * dy + (double)dz * dz + (double)dw * dw;
    }
    s_out[(size_t)p * NN + j] = (double)gum[(size_t)p * NN + j] - acc;
  }
}

// ---------------------------------------------------------------- kernel 2
// B half-sums: B_h[p][j] = sum_{i in half h} |s_j - s_i|  (f64)
// grid = NP * 4(chunk of 256 j) * 2(half of i) = 512 blocks
__global__ __launch_bounds__(256) void k_bsum(const double* __restrict__ s,
                                              double* __restrict__ B0,
                                              double* __restrict__ B1) {
  int b = blockIdx.x;
  int p = b >> 3, chunk = (b >> 1) & 3, half = b & 1;
  __shared__ double ss[512];
  int tid = threadIdx.x;
  const double* srow = s + (size_t)p * NN + half * 512;
  ss[tid] = srow[tid];
  ss[tid + 256] = srow[tid + 256];
  __syncthreads();
  double sj = s[(size_t)p * NN + chunk * 256 + tid];
  double a0 = 0.0, a1 = 0.0, a2 = 0.0, a3 = 0.0;
#pragma unroll 4
  for (int i = 0; i < 512; i += 4) {
    a0 += fabs(sj - ss[i + 0]);
    a1 += fabs(sj - ss[i + 1]);
    a2 += fabs(sj - ss[i + 2]);
    a3 += fabs(sj - ss[i + 3]);
  }
  double* Bd = half ? B1 : B0;
  Bd[(size_t)p * NN + chunk * 256 + tid] = (a0 + a1) + (a2 + a3);
}

// ---------------------------------------------------------------- kernel 3
// per (p, r): m_pr = max_i t_i,  Z_pr = sum_i exp(t_i - m_pr)
// t_i = c_r * s_i - B_i,  c_r = 1023 - 2r
__global__ __launch_bounds__(256) void k_mz(const double* __restrict__ s,
                                            const double* __restrict__ B0,
                                            const double* __restrict__ B1,
                                            double* __restrict__ mrow,
                                            float* __restrict__ zrow) {
  int b = blockIdx.x;
  int p = b >> 4, r = b & 15;
  double cr = (double)(1023 - 2 * r);
  int tid = threadIdx.x;
  size_t base = (size_t)p * NN;
  double t[4];
  double mx = -1e300;
#pragma unroll
  for (int k = 0; k < 4; ++k) {
    int i = tid + k * 256;
    t[k] = cr * s[base + i] - (B0[base + i] + B1[base + i]);
    mx = fmax(mx, t[k]);
  }
  for (int off = 32; off; off >>= 1) mx = fmax(mx, __shfl_down(mx, off, 64));
  int wave = tid >> 6, lane = tid & 63;
  __shared__ double redm[4];
  if (lane == 0) redm[wave] = mx;
  __syncthreads();
  double m = fmax(fmax(redm[0], redm[1]), fmax(redm[2], redm[3]));
  float z = 0.f;
#pragma unroll
  for (int k = 0; k < 4; ++k) z += __expf((float)(t[k] - m));
  for (int off = 32; off; off >>= 1) z += __shfl_down(z, off, 64);
  __shared__ float redz[4];
  if (lane == 0) redz[wave] = z;
  __syncthreads();
  if (tid == 0) {
    mrow[p * KTOP + r] = m;
    zrow[p * KTOP + r] = (redz[0] + redz[1]) + (redz[2] + redz[3]);
  }
}

// ---------------------------------------------------------------- kernel 4
// out[p][j] = sum_r exp(t_j(r) - m_pr) / Z_pr
__global__ __launch_bounds__(256) void k_out(const double* __restrict__ s,
                                             const double* __restrict__ B0,
                                             const double* __restrict__ B1,
                                             const double* __restrict__ mrow,
                                             const float* __restrict__ zrow,
                                             float* __restrict__ out) {
  int b = blockIdx.x;
  int p = b >> 2, chunk = b & 3;
  __shared__ double mloc[KTOP];
  __shared__ float izloc[KTOP];
  int tid = threadIdx.x;
  if (tid < KTOP) {
    mloc[tid] = mrow[p * KTOP + tid];
    izloc[tid] = 1.0f / zrow[p * KTOP + tid];
  }
  __syncthreads();
  int j = chunk * 256 + tid;
  size_t idx = (size_t)p * NN + j;
  double sj = s[idx];
  double bj = B0[idx] + B1[idx];
  float acc = 0.f;
#pragma unroll
  for (int r = 0; r < KTOP; ++r) {
    double t = (double)(1023 - 2 * r) * sj - bj;
    acc += __expf((float)(t - mloc[r])) * izloc[r];
  }
  out[idx] = acc;
}

extern "C" void kernel_launch(void* const* d_in, const int* in_sizes, int n_in,
                              void* d_out, int out_size, void* d_ws, size_t ws_size,
                              hipStream_t stream) {
  const float* q   = (const float*)d_in[0];   // [32,128]
  const float* nb  = (const float*)d_in[1];   // [1024,128]
  const float* gum = (const float*)d_in[2];   // [2,32,1024]
  float* out = (float*)d_out;                 // [2,32,1024]

  char* ws = (char*)d_ws;
  double* s    = (double*)ws;                                   // 512 KiB
  double* B0   = (double*)(ws + (size_t)NP * NN * 8);           // 512 KiB
  double* B1   = (double*)(ws + (size_t)NP * NN * 16);          // 512 KiB
  double* mrow = (double*)(ws + (size_t)NP * NN * 24);          // 8 KiB
  float*  zrow = (float*)(ws + (size_t)NP * NN * 24 + NP * KTOP * 8);  // 4 KiB

  k_scores<<<NP, 256, 0, stream>>>(q, nb, gum, s);
  k_bsum<<<NP * 8, 256, 0, stream>>>(s, B0, B1);
  k_mz<<<NP * KTOP, 256, 0, stream>>>(s, B0, B1, mrow, zrow);
  k_out<<<NP * 4, 256, 0, stream>>>(s, B0, B1, mrow, zrow, out);
}